// Round 9
// baseline (493.526 us; speedup 1.0000x reference)
//
#include <hip/hip_runtime.h>

// Shapes (fixed): B=4, N=256, F=6, H=128, D=256, B*N=1024
// All tensors fp32. out = concat(adj_pred [4,256,256], feat_pred [4,256,6]).
// Single persistent kernel, 256 blocks x 256 threads, grid barriers via atomics.

typedef float v4f __attribute__((ext_vector_type(4)));
typedef short v8s __attribute__((ext_vector_type(8)));

#define NBLK 256

__device__ __forceinline__ unsigned short f2bs(float f) {
    union { float f; unsigned int u; } v;
    v.f = f;
    return (unsigned short)((v.u + 0x7fffu + ((v.u >> 16) & 1u)) >> 16);
}

// generation-counter grid barrier (all NBLK blocks co-resident by construction)
__device__ void gbar(int* cnt, int* gen) {
    __syncthreads();
    if (threadIdx.x == 0) {
        __threadfence();
        int g = atomicAdd(gen, 0);
        if (atomicAdd(cnt, 1) == NBLK - 1) {
            atomicExch(cnt, 0);
            __threadfence();
            atomicAdd(gen, 1);
        } else {
            long it = 0;
            while (atomicAdd(gen, 0) == g) {
                if (++it > 100000000L) break;   // hedge: never hard-hang
            }
        }
    }
    __syncthreads();
    __threadfence();
}

// tiled GEMM over a tile-grid, strided by block: C = A@B [+bias][relu]
//  stat: consumer-BN affine (raw sum/sumsq in stat) + relu applied to A
//  ostat: per-column sum/sumsq of C accumulated via atomics
__device__ void dev_tgemm(const float* A, const float* B, const float* bias,
                          const float* stat, const float* g, const float* beta,
                          float* ostat, float* C,
                          int M, int K, int N, int relu,
                          int sA, int sB, int sC,
                          int tiles_n, int tiles_m, int tiles_tot,
                          float* smem) {
    float* As = smem;          // [16][33]
    float* Bs = smem + 528;    // [16][33]
    int tid = threadIdx.x;
    int tx = tid & 15, ty = tid >> 4;
    for (int t = blockIdx.x; t < tiles_tot; t += NBLK) {
        __syncthreads();
        int bx = t % tiles_n;
        int tmp = t / tiles_n;
        int by = tmp % tiles_m;
        int bz = tmp / tiles_m;
        int m0 = by * 32, n0 = bx * 32;
        const float* Ab = A + (long)bz * sA;
        const float* Bb = B + (long)bz * sB;
        float* Cb = C + (long)bz * sC;
        float c00 = 0.f, c01 = 0.f, c10 = 0.f, c11 = 0.f;
        for (int k0 = 0; k0 < K; k0 += 16) {
            for (int l = 0; l < 2; l++) {
                int idx = tid + l * 256;
                int kk = idx & 15, mm = idx >> 4;        // A: coalesced along K
                int kg = k0 + kk;
                float v = Ab[(long)(m0 + mm) * K + kg];
                if (stat != 0) {                          // BN affine + relu
                    float mu = stat[kg] * (1.f / 1024.f);
                    float vr = stat[128 + kg] * (1.f / 1024.f) - mu * mu;
                    float sc = rsqrtf(vr + 1e-5f) * g[kg];
                    v = (v - mu) * sc + beta[kg];
                    if (v < 0.f) v = 0.f;
                }
                As[kk * 33 + mm] = v;
                int nn2 = idx & 31, kk2 = idx >> 5;       // B: coalesced along N
                Bs[kk2 * 33 + nn2] = Bb[(long)(k0 + kk2) * N + n0 + nn2];
            }
            __syncthreads();
            #pragma unroll
            for (int kk = 0; kk < 16; kk++) {
                float A0 = As[kk * 33 + ty * 2], A1 = As[kk * 33 + ty * 2 + 1];
                float B0 = Bs[kk * 33 + tx * 2], B1 = Bs[kk * 33 + tx * 2 + 1];
                c00 += A0 * B0; c01 += A0 * B1; c10 += A1 * B0; c11 += A1 * B1;
            }
            __syncthreads();
        }
        int mm = m0 + ty * 2, nn = n0 + tx * 2;
        float r00 = c00, r01 = c01, r10 = c10, r11 = c11;
        if (bias != 0) {
            float bq0 = bias[nn], bq1 = bias[nn + 1];
            r00 += bq0; r01 += bq1; r10 += bq0; r11 += bq1;
        }
        if (relu) {
            if (r00 < 0.f) r00 = 0.f;
            if (r01 < 0.f) r01 = 0.f;
            if (r10 < 0.f) r10 = 0.f;
            if (r11 < 0.f) r11 = 0.f;
        }
        Cb[(long)mm * N + nn] = r00;
        Cb[(long)mm * N + nn + 1] = r01;
        Cb[(long)(mm + 1) * N + nn] = r10;
        Cb[(long)(mm + 1) * N + nn + 1] = r11;

        if (ostat != 0) {                                 // column stats of C
            float* sred = As;
            float* qred = Bs;
            __syncthreads();
            sred[(tx * 2 + 0) * 16 + ty] = r00 + r10;
            qred[(tx * 2 + 0) * 16 + ty] = r00 * r00 + r10 * r10;
            sred[(tx * 2 + 1) * 16 + ty] = r01 + r11;
            qred[(tx * 2 + 1) * 16 + ty] = r01 * r01 + r11 * r11;
            __syncthreads();
            if (tid < 32) {
                float s = 0.f, q = 0.f;
                for (int u = 0; u < 16; u++) {
                    s += sred[tid * 16 + u];
                    q += qred[tid * 16 + u];
                }
                atomicAdd(&ostat[n0 + tid], s);
                atomicAdd(&ostat[128 + n0 + tid], q);
            }
        }
    }
}

__global__ void k_all(const float* x, const float* adj,
                      const float* W1, const float* b1,
                      const float* W2, const float* b2,
                      const float* W3, const float* b3,
                      const float* g1, const float* be1,
                      const float* g2, const float* be2,
                      const float* e1w, const float* e1b,
                      const float* e2w, const float* e2b,
                      const float* e3w, const float* e3b,
                      const float* f1w, const float* f1b,
                      const float* f2w, const float* f2b_,
                      const float* f3w, const float* f3b,
                      float* ws, float* out) {
    __shared__ float smem[8448];                 // 33792 B, unioned per stage

    int* cnt = (int*)ws;
    int* gen = cnt + 1;
    float* st1 = ws + 64;                        // sum/sumsq of h1 (zeroed)
    float* st2 = ws + 320;                       // sum/sumsq of h2 (zeroed)
    float* dg  = ws + 576;                       // 1024
    float* An  = ws + 2048;                      // 262144
    float* buf = An + 262144;                    // 262144
    float* hb  = buf + 262144;                   // 262144
    float* lg  = hb + 262144;                    // 262144
    float* h1  = lg + 262144;                    // 131072 (later reused as f1)
    float* h2  = h1 + 131072;                    // 131072
    float* hi  = h2 + 131072;                    // 131072
    float* hj  = hi + 131072;                    // 131072 (contiguous after hi)

    int tid = threadIdx.x;
    int blk = blockIdx.x;

    // ---- S0: degree (4 rows/block, 64 lanes/row) + buf = x@W1 ----
    {
        int row = blk * 4 + (tid >> 6);
        int lane = tid & 63;
        const float* ap = adj + (long)row * 256;
        float s = ap[lane] + ap[lane + 64] + ap[lane + 128] + ap[lane + 192];
        smem[tid] = s;
        __syncthreads();
        for (int o = 32; o > 0; o >>= 1) {
            if (lane < o) smem[tid] += smem[tid + o];
            __syncthreads();
        }
        if (lane == 0) {
            float t = smem[tid] + 1.f;
            if (t < 1.f) t = 1.f;
            dg[row] = rsqrtf(t);
        }
        __syncthreads();
        for (int p = 0; p < 2; p++) {
            int idx = blk * 256 + tid + p * 65536;   // 131072 outputs
            int m = idx >> 7, n = idx & 127;
            float s2 = 0.f;
            for (int k = 0; k < 6; k++) s2 += x[m * 6 + k] * W1[k * 128 + n];
            buf[idx] = s2;
        }
    }
    gbar(cnt, gen);

    // ---- S1: An = d_i * (adj + I) * d_j ----
    for (int p = 0; p < 4; p++) {
        int idx = blk * 256 + tid + p * 65536;       // 262144
        int b = idx >> 16, i = (idx >> 8) & 255, j = idx & 255;
        float v = adj[idx] + ((i == j) ? 1.f : 0.f);
        An[idx] = dg[b * 256 + i] * v * dg[b * 256 + j];
    }
    gbar(cnt, gen);

    // ---- S2: h1 = An@buf + b1 (+stats->st1) ----
    dev_tgemm(An, buf, b1, 0, 0, 0, st1, h1, 256, 256, 128, 0,
              65536, 32768, 32768, 4, 8, 128, smem);
    gbar(cnt, gen);

    // ---- S3: buf = BN(h1)@W2 ----
    dev_tgemm(h1, W2, 0, st1, g1, be1, 0, buf, 1024, 128, 128, 0,
              0, 0, 0, 4, 32, 128, smem);
    gbar(cnt, gen);

    // ---- S4: h2 = An@buf + b2 (+stats->st2) ----
    dev_tgemm(An, buf, b2, 0, 0, 0, st2, h2, 256, 256, 128, 0,
              65536, 32768, 32768, 4, 8, 128, smem);
    gbar(cnt, gen);

    // ---- S5: buf = BN(h2)@W3 ----
    dev_tgemm(h2, W3, 0, st2, g2, be2, 0, buf, 1024, 128, 256, 0,
              0, 0, 0, 8, 32, 256, smem);
    gbar(cnt, gen);

    // ---- S6: hb = relu(An@buf + b3) ----
    dev_tgemm(An, buf, b3, 0, 0, 0, 0, hb, 256, 256, 256, 1,
              65536, 65536, 65536, 8, 8, 256, smem);
    gbar(cnt, gen);

    // ---- S7: hi/hj = hb@e1w halves (batch-2); h1 <- f1 = relu(hb@f1w+f1b) ----
    dev_tgemm(hb, e1w, 0, 0, 0, 0, 0, hi, 1024, 256, 128, 0,
              0, 32768, 131072, 4, 32, 256, smem);
    dev_tgemm(hb, f1w, f1b, 0, 0, 0, 0, h1, 1024, 256, 128, 1,
              0, 0, 0, 4, 32, 128, smem);
    gbar(cnt, gen);

    // ---- S8: MFMA pair decoder (4 units/block) + feature f2/f3 ----
    {
        unsigned short* bfr = (unsigned short*)smem;   // 8192 ushort = 16 KB
        float* red = smem + 4096;                      // 4096 floats
        float* pre_sh = smem + 8192;                   // 128 floats
        int lane = tid & 63, wv = tid >> 6;
        int col = lane & 15, quad = lane >> 4;

        // stage e2w -> bf16 B-fragments, once per block
        for (int s = tid; s < 1024; s += 256) {
            int base = s * 8;
            int k = base >> 6;
            int n0 = base & 63;
            int kc = k >> 5, q = (k & 31) >> 3, t = k & 7;
            for (int u = 0; u < 8; u++) {
                int n = n0 + u;
                int nt = n >> 4, c2 = n & 15;
                bfr[(((nt * 4 + kc) * 64) + q * 16 + c2) * 8 + t] =
                    f2bs(e2w[base + u]);
            }
        }
        float e2bv[4], e3wv[4];
        for (int nt = 0; nt < 4; nt++) {
            e2bv[nt] = e2b[nt * 16 + col];
            e3wv[nt] = e3w[nt * 16 + col];
        }
        float e3bv = e3b[0];

        for (int u = 0; u < 4; u++) {
            int bi = blk * 4 + u, b = bi >> 8;
            __syncthreads();
            if (tid < 128) pre_sh[tid] = hi[bi * 128 + tid] + e1b[tid];
            __syncthreads();
            float preR[4][8];
            for (int kc = 0; kc < 4; kc++)
                for (int t = 0; t < 8; t++)
                    preR[kc][t] = pre_sh[kc * 32 + quad * 8 + t];
            v4f acc[4][4];
            for (int ms = 0; ms < 4; ms++)
                for (int nt = 0; nt < 4; nt++) {
                    v4f z = {0.f, 0.f, 0.f, 0.f};
                    acc[ms][nt] = z;
                }
            const float* hjb = hj + b * 32768;
            for (int kc = 0; kc < 4; kc++) {
                v8s bfrag[4];
                for (int nt = 0; nt < 4; nt++)
                    bfrag[nt] = *(const v8s*)&bfr[(((nt * 4 + kc) * 64) + lane) * 8];
                for (int ms = 0; ms < 4; ms++) {
                    int j = wv * 64 + ms * 16 + col;
                    const float* hp = hjb + j * 128 + kc * 32 + quad * 8;
                    v8s af;
                    for (int t = 0; t < 8; t++) {
                        float p = preR[kc][t] + hp[t];
                        p = (p > 0.f) ? p : 0.f;
                        af[t] = (short)f2bs(p);
                    }
                    for (int nt = 0; nt < 4; nt++)
                        acc[ms][nt] = __builtin_amdgcn_mfma_f32_16x16x32_bf16(
                            af, bfrag[nt], acc[ms][nt], 0, 0, 0);
                }
            }
            for (int ms = 0; ms < 4; ms++) {
                for (int r = 0; r < 4; r++) {
                    float s = 0.f;
                    for (int nt = 0; nt < 4; nt++) {
                        float v = acc[ms][nt][r] + e2bv[nt];
                        if (v > 0.f) s += v * e3wv[nt];
                    }
                    red[wv * 1024 + (ms * 16 + quad * 4 + r) * 16 + col] = s;
                }
            }
            __syncthreads();
            float s = e3bv;
            for (int c = 0; c < 16; c++) s += red[tid * 16 + c];
            lg[bi * 256 + tid] = s;
        }
    }
    __syncthreads();
    // feature decoder: 4 rows/block; f2 into LDS, then f3 -> out
    {
        int r0 = blk * 4;
        float* f2row = smem;                    // 512 floats (bfr area, free now)
        for (int p = 0; p < 2; p++) {
            int idx = tid + p * 256;            // 0..511
            int r = r0 + (idx >> 7), n = idx & 127;
            float s = f2b_[n];
            const float* f1r = h1 + (long)r * 128;
            for (int k = 0; k < 128; k++) s += f1r[k] * f2w[k * 128 + n];
            if (s < 0.f) s = 0.f;
            f2row[idx] = s;
        }
        __syncthreads();
        if (tid < 24) {
            int r = tid / 6, c = tid % 6;
            float s = f3b[c];
            const float* fr = f2row + r * 128;
            for (int k = 0; k < 128; k++) s += fr[k] * f3w[k * 6 + c];
            out[262144 + (r0 + r) * 6 + c] = s;
        }
    }
    gbar(cnt, gen);

    // ---- S9: symmetrize + sigmoid ----
    for (int p = 0; p < 4; p++) {
        int idx = blk * 256 + tid + p * 65536;   // 262144
        int b = idx >> 16, i = (idx >> 8) & 255, j = idx & 255;
        float v = 0.5f * (lg[idx] + lg[(b << 16) + (j << 8) + i]);
        out[idx] = 1.f / (1.f + expf(-v));
    }
}

extern "C" void kernel_launch(void* const* d_in, const int* in_sizes, int n_in,
                              void* d_out, int out_size, void* d_ws, size_t ws_size,
                              hipStream_t stream) {
    if (ws_size < (size_t)1700000 * 4) {
        hipMemsetAsync(d_out, 0x60, 4096, stream);   // diagnostic
        return;
    }
    // zero barrier state + BN accumulators (ctrl 64 + st1 256 + st2 256 floats)
    hipMemsetAsync(d_ws, 0, 576 * 4, stream);

    k_all<<<NBLK, 256, 0, stream>>>(
        (const float*)d_in[0],  (const float*)d_in[1],
        (const float*)d_in[2],  (const float*)d_in[3],
        (const float*)d_in[4],  (const float*)d_in[5],
        (const float*)d_in[6],  (const float*)d_in[7],
        (const float*)d_in[8],  (const float*)d_in[9],
        (const float*)d_in[10], (const float*)d_in[11],
        (const float*)d_in[12], (const float*)d_in[13],
        (const float*)d_in[14], (const float*)d_in[15],
        (const float*)d_in[16], (const float*)d_in[17],
        (const float*)d_in[18], (const float*)d_in[19],
        (const float*)d_in[20], (const float*)d_in[21],
        (const float*)d_in[22], (const float*)d_in[23],
        (float*)d_ws, (float*)d_out);
}